// Round 5
// baseline (1604.811 us; speedup 1.0000x reference)
//
#include <hip/hip_runtime.h>
#include <cstddef>

#define SLOPE 0.2f

typedef unsigned short u16;
typedef __attribute__((ext_vector_type(8))) short short8v;
typedef __attribute__((ext_vector_type(8))) __bf16 bf16x8;
typedef __attribute__((ext_vector_type(4))) float f32x4;

__device__ __forceinline__ u16 f2bf(float x) {
  unsigned u = __float_as_uint(x);
  unsigned r = (u + 0x7fffu + ((u >> 16) & 1u)) >> 16;  // RNE
  return (u16)r;
}
__device__ __forceinline__ float bf2f(u16 h) {
  return __uint_as_float(((unsigned)h) << 16);
}
// T1 XCD-chunked swizzle (m204 bijective form, nwg % 8 == 0):
// HW round-robins dispatch index -> XCD; this gives logical chunk r to XCD r.
__device__ __forceinline__ int xcd_swz(int orig, int cpx) {
  return (orig & 7) * cpx + (orig >> 3);
}

// ---------------- dec0: h0[b][128] = leaky(x @ W0^T + b0) ----------------
// wave-per-output: grid (16 b, 32 co-groups), block 256 = 4 waves; lane = k-quad
__global__ __launch_bounds__(256) void k_dec0(const float* __restrict__ x,
    const float* __restrict__ w, const float* __restrict__ bias,
    float* __restrict__ h0) {
  const int t = threadIdx.x, lane = t & 63, wv = t >> 6;
  const int b = blockIdx.x, co = blockIdx.y * 4 + wv;
  const float4 xv = *(const float4*)(x + b * 256 + lane * 4);
  const float4 wvv = *(const float4*)(w + (size_t)co * 256 + lane * 4);
  float s = xv.x * wvv.x + xv.y * wvv.y + xv.z * wvv.z + xv.w * wvv.w;
#pragma unroll
  for (int m = 32; m >= 1; m >>= 1) s += __shfl_xor(s, m);
  if (lane == 0) {
    float a = s + bias[co];
    h0[b * 128 + co] = a > 0.f ? a : SLOPE * a;
  }
}

// ---------------- L1: deconv 128->128, 1^3 -> 2^3 ----------------
// Only taps kd=1+pz etc ever touch real input (input voxel 0).
// h1 layout: [p][b][vox(=cls)][128]
__global__ __launch_bounds__(256) void k_l1(const float* __restrict__ h0,
    const float* __restrict__ w1, const float* __restrict__ b1,
    float* __restrict__ h1) {
  __shared__ float wl[4][8][33];  // [ci-chunk][tap8][co32+pad]
  const int t = threadIdx.x, cog = blockIdx.x, p = blockIdx.z;
  const int co = t & 31, sl = t >> 5;
  const int cog32 = cog * 32;
  float acc[2][8];
  const float bv = b1[p * 128 + cog32 + co];
#pragma unroll
  for (int i = 0; i < 2; ++i)
#pragma unroll
    for (int j = 0; j < 8; ++j) acc[i][j] = bv;

  for (int ci0 = 0; ci0 < 128; ci0 += 4) {
    __syncthreads();
    for (int g = t; g < 1024; g += 256) {
      const int tp = g & 7, c = (g >> 3) & 31, cc = g >> 8;
      const int kd = 1 + ((tp >> 2) & 1), kh = 1 + ((tp >> 1) & 1), kw = 1 + (tp & 1);
      wl[cc][tp][c] =
          w1[(((size_t)p * 128 + ci0 + cc) * 128 + cog32 + c) * 64 + kd * 16 + kh * 4 + kw];
    }
    __syncthreads();
    float xr[2][4];
#pragma unroll
    for (int bb = 0; bb < 2; ++bb) {
      const int b = sl * 2 + bb;
      const float4 v = *(const float4*)(h0 + b * 128 + ci0);
      xr[bb][0] = v.x; xr[bb][1] = v.y; xr[bb][2] = v.z; xr[bb][3] = v.w;
    }
#pragma unroll
    for (int cls = 0; cls < 8; ++cls) {
#pragma unroll
      for (int cc = 0; cc < 4; ++cc) {
        const float wv = wl[cc][cls][co];
        acc[0][cls] = fmaf(xr[0][cc], wv, acc[0][cls]);
        acc[1][cls] = fmaf(xr[1][cc], wv, acc[1][cls]);
      }
    }
  }
#pragma unroll
  for (int bb = 0; bb < 2; ++bb)
#pragma unroll
    for (int cls = 0; cls < 8; ++cls) {
      const int b = sl * 2 + bb;
      float a = acc[bb][cls];
      a = a > 0.f ? a : SLOPE * a;
      h1[(((size_t)p * 16 + b) * 8 + cls) * 128 + cog32 + co] = a;
    }
}

// ---------------- L2: deconv 128->64, 2^3 -> 4^3, fp32 VALU, split-bf16 output ----------------
// in [p][b][8][128] f32 -> out hi/lo bf16 [p][b][64][64]
// 1-D grid 256 = XCD-swizzled (p, bg)
template <int CIN, int DIN>
__global__ __launch_bounds__(256) void k_deconv_split(const float* __restrict__ in,
    const float* __restrict__ w, const float* __restrict__ bias,
    u16* __restrict__ ohi, u16* __restrict__ olo) {
  constexpr int DOUT = 2 * DIN;
  constexpr int NVOXI = DIN * DIN * DIN;
  constexpr int NVOXO = DOUT * DOUT * DOUT;
  __shared__ float inl[4][64][2];
  __shared__ float wl[2][64][65];
  const int t = threadIdx.x;
  const int wg = xcd_swz(blockIdx.x, 32);  // 256 blocks: 32 per XCD chunk
  const int p = wg >> 2, bg = wg & 3;      // 8 p's per XCD, 4 bg blocks each
  const int co = t & 63, sl = t >> 6;
  const int b = bg * 4 + sl;

  const int sv = t & 63;
  const int lz = sv >> 4, ly = (sv >> 2) & 3, lx = sv & 3;
  const int iz = lz - 1, iy = ly - 1, ix = lx - 1;  // tile base -1 (single tile)
  const bool okst = (unsigned)iz < (unsigned)DIN && (unsigned)iy < (unsigned)DIN &&
                    (unsigned)ix < (unsigned)DIN;
  const float* stp =
      in + (((size_t)p * 16 + b) * NVOXI + ((iz * DIN + iy) * DIN + ix)) * CIN;

  float acc[8][8];
  const float bv = bias[p * 64 + co];
#pragma unroll
  for (int c = 0; c < 8; ++c)
#pragma unroll
    for (int v = 0; v < 8; ++v) acc[c][v] = bv;

  for (int ci0 = 0; ci0 < CIN; ci0 += 2) {
    __syncthreads();
    {
      float2 v = make_float2(0.f, 0.f);
      if (okst) v = *(const float2*)(stp + ci0);
      *(float2*)&inl[sl][sv][0] = v;
    }
#pragma unroll
    for (int g4 = 0; g4 < 8; ++g4) {
      const int g = t + g4 * 256;
      const int t4 = g & 15, c = (g >> 4) & 63, cc = g >> 10;
      const float4 v =
          *(const float4*)(w + (((size_t)p * CIN + ci0 + cc) * 64 + c) * 64 + t4 * 4);
      wl[cc][t4 * 4 + 0][c] = v.x; wl[cc][t4 * 4 + 1][c] = v.y;
      wl[cc][t4 * 4 + 2][c] = v.z; wl[cc][t4 * 4 + 3][c] = v.w;
    }
    __syncthreads();
#pragma unroll
    for (int cls = 0; cls < 8; ++cls) {
      const int pz = (cls >> 2) & 1, py = (cls >> 1) & 1, px = cls & 1;
      float in3[2][3][3][3];
#pragma unroll
      for (int az = 0; az < 3; ++az)
#pragma unroll
        for (int ay = 0; ay < 3; ++ay)
#pragma unroll
          for (int ax = 0; ax < 3; ++ax) {
            const int vf = ((pz + az) * 4 + (py + ay)) * 4 + (px + ax);
            const float2 v2 = *(const float2*)&inl[sl][vf][0];
            in3[0][az][ay][ax] = v2.x;
            in3[1][az][ay][ax] = v2.y;
          }
#pragma unroll
      for (int s = 0; s < 8; ++s) {
        const int sz = (s >> 2) & 1, sy = (s >> 1) & 1, sx = s & 1;
        const int tap =
            (3 - pz - 2 * sz) * 16 + (3 - py - 2 * sy) * 4 + (3 - px - 2 * sx);
#pragma unroll
        for (int cc = 0; cc < 2; ++cc) {
          const float wv = wl[cc][tap][co];
#pragma unroll
          for (int v = 0; v < 8; ++v) {
            const int vz = (v >> 2) & 1, vy = (v >> 1) & 1, vx = v & 1;
            acc[cls][v] = fmaf(in3[cc][vz + sz][vy + sy][vx + sx], wv, acc[cls][v]);
          }
        }
      }
    }
  }
#pragma unroll
  for (int cls = 0; cls < 8; ++cls) {
    const int pz = (cls >> 2) & 1, py = (cls >> 1) & 1, px = cls & 1;
#pragma unroll
    for (int v = 0; v < 8; ++v) {
      const int vz = (v >> 2) & 1, vy = (v >> 1) & 1, vx = v & 1;
      const int oz = 2 * vz + pz, oy = 2 * vy + py, ox = 2 * vx + px;
      float a = acc[cls][v];
      a = a > 0.f ? a : SLOPE * a;
      const size_t idx =
          (((size_t)p * 16 + b) * NVOXO + (oz * DOUT + oy) * DOUT + ox) * 64 + co;
      const u16 hi = f2bf(a);
      ohi[idx] = hi;
      olo[idx] = f2bf(a - bf2f(hi));
    }
  }
}

// ---------------- prep: w3 [p][ci][co][tap] f32 -> wt3 hi/lo bf16 [p][tap][co][ci] ----------------
__global__ __launch_bounds__(256) void k_prep_w3(const float* __restrict__ w3,
    u16* __restrict__ whi, u16* __restrict__ wlo) {
  __shared__ float tr[64][65];  // [tap][ci]
  const int p = blockIdx.x, cg = blockIdx.y;
  const int t = threadIdx.x;
  for (int c = 0; c < 16; ++c) {
    const int co = cg * 16 + c;
    __syncthreads();
#pragma unroll
    for (int it = 0; it < 4; ++it) {
      const int idx = t + it * 256;           // 1024 float4 slots: ci(64) x tq(16)
      const int ci = idx >> 4, tq = idx & 15;
      const float4 v = *(const float4*)(w3 + (((size_t)p * 64 + ci) * 64 + co) * 64 + tq * 4);
      tr[tq * 4 + 0][ci] = v.x; tr[tq * 4 + 1][ci] = v.y;
      tr[tq * 4 + 2][ci] = v.z; tr[tq * 4 + 3][ci] = v.w;
    }
    __syncthreads();
    const int tap = t >> 2, cq = t & 3;       // thread: 16 ci
    u16 hi[16], lo[16];
#pragma unroll
    for (int j = 0; j < 16; ++j) {
      const float v = tr[tap][cq * 16 + j];
      hi[j] = f2bf(v);
      lo[j] = f2bf(v - bf2f(hi[j]));
    }
    const size_t ob = (((size_t)p * 64 + tap) * 64 + co) * 64 + cq * 16;
#pragma unroll
    for (int h = 0; h < 2; ++h) {
      *(short8v*)(whi + ob + h * 8) = *(const short8v*)&hi[h * 8];
      *(short8v*)(wlo + ob + h * 8) = *(const short8v*)&lo[h * 8];
    }
  }
}

// ---------------- L3 via MFMA: 64->64, 4^3 -> 8^3, split-bf16, T14 async-stage ----------------
// in hi/lo [p][b][64][64]; weights hi/lo [p][tap][co][ci]; out f32 [p][b][512][64]
// 1-D grid 2048 = XCD-swizzled (p, cls, bg); block 256 = 4 waves (wave = batch)
#define ASTR 40  // LDS row stride in shorts (80B = 5 x 16B units -> conflict-free)
struct L3Stage {
  short8v vh[4], vl[4], bh, bl;
};
__global__ __launch_bounds__(256, 2) void k_l3_mfma(const u16* __restrict__ inhi,
    const u16* __restrict__ inlo, const u16* __restrict__ whi,
    const u16* __restrict__ wlo, const float* __restrict__ bias,
    float* __restrict__ out) {
  __shared__ __align__(16) short Ah[256 * ASTR];
  __shared__ __align__(16) short Al[256 * ASTR];
  __shared__ __align__(16) short Bh[64 * ASTR];
  __shared__ __align__(16) short Bl[64 * ASTR];
  const int t = threadIdx.x;
  const int wg = xcd_swz(blockIdx.x, 256);  // 2048 blocks: 256 per XCD chunk
  const int p = wg >> 5, cls = (wg >> 2) & 7, bg = wg & 3;  // 8 p's per XCD
  const int pz = (cls >> 2) & 1, py = (cls >> 1) & 1, px = cls & 1;
  const int lane = t & 63, wv = t >> 6;
  const int b = bg * 4 + wv;

  // per-thread static staging geometry
  const int r = t;
  const int rb = bg * 4 + (r >> 6);
  const int cv = r & 63, vz = cv >> 4, vy = (cv >> 2) & 3, vx = cv & 3;
  const int sco = t >> 2, skq = t & 3;

  // issue global loads for k-step kt into registers (no LDS, no waits)
  auto issue = [&](int kt, L3Stage& st) {
    const int s = kt >> 1, ci0 = (kt & 1) * 32;
    const int sz = (s >> 2) & 1, sy = (s >> 1) & 1, sx = s & 1;
    const int tap = (3 - pz - 2 * sz) * 16 + (3 - py - 2 * sy) * 4 + (3 - px - 2 * sx);
    const int iz = vz + pz + sz - 1, iy = vy + py + sy - 1, ix = vx + px + sx - 1;
    const bool ok = (unsigned)iz < 4u && (unsigned)iy < 4u && (unsigned)ix < 4u;
    if (ok) {
      const size_t base =
          (((size_t)p * 16 + rb) * 64 + (iz * 4 + iy) * 4 + ix) * 64 + ci0;
#pragma unroll
      for (int j = 0; j < 4; ++j) {
        st.vh[j] = *(const short8v*)(inhi + base + j * 8);
        st.vl[j] = *(const short8v*)(inlo + base + j * 8);
      }
    } else {
#pragma unroll
      for (int j = 0; j < 4; ++j) { st.vh[j] = (short8v)0; st.vl[j] = (short8v)0; }
    }
    const size_t wb = (((size_t)p * 64 + tap) * 64 + sco) * 64 + ci0 + skq * 8;
    st.bh = *(const short8v*)(whi + wb);
    st.bl = *(const short8v*)(wlo + wb);
  };

  f32x4 acc[4][4];
#pragma unroll
  for (int nf = 0; nf < 4; ++nf) {
    const float bv = bias[p * 64 + nf * 16 + (lane & 15)];
#pragma unroll
    for (int mf = 0; mf < 4; ++mf) acc[mf][nf] = {bv, bv, bv, bv};
  }

  L3Stage cur, nxt;
  issue(0, cur);
  for (int kt = 0; kt < 16; ++kt) {
    __syncthreads();  // readers of previous k-step done
    // T14: issue NEXT k-step's loads before writing current (stays in flight
    // across the vmcnt-partial wait + MFMA phase)
    if (kt < 15) issue(kt + 1, nxt);
    // write current regs -> LDS (compiler waits only on cur's loads)
#pragma unroll
    for (int j = 0; j < 4; ++j) {
      *(short8v*)&Ah[r * ASTR + j * 8] = cur.vh[j];
      *(short8v*)&Al[r * ASTR + j * 8] = cur.vl[j];
    }
    *(short8v*)&Bh[sco * ASTR + skq * 8] = cur.bh;
    *(short8v*)&Bl[sco * ASTR + skq * 8] = cur.bl;
    __syncthreads();  // tile ready
    const int fr = lane & 15, kq = lane >> 4;
    short8v a_h[4], a_l[4];
#pragma unroll
    for (int mf = 0; mf < 4; ++mf) {
      const int row = wv * 64 + mf * 16 + fr;
      a_h[mf] = *(const short8v*)&Ah[row * ASTR + kq * 8];
      a_l[mf] = *(const short8v*)&Al[row * ASTR + kq * 8];
    }
#pragma unroll
    for (int nf = 0; nf < 4; ++nf) {
      const int col = nf * 16 + fr;
      const short8v b_h = *(const short8v*)&Bh[col * ASTR + kq * 8];
      const short8v b_l = *(const short8v*)&Bl[col * ASTR + kq * 8];
#pragma unroll
      for (int mf = 0; mf < 4; ++mf) {
        acc[mf][nf] = __builtin_amdgcn_mfma_f32_16x16x32_bf16(
            __builtin_bit_cast(bf16x8, a_h[mf]), __builtin_bit_cast(bf16x8, b_h),
            acc[mf][nf], 0, 0, 0);
        acc[mf][nf] = __builtin_amdgcn_mfma_f32_16x16x32_bf16(
            __builtin_bit_cast(bf16x8, a_h[mf]), __builtin_bit_cast(bf16x8, b_l),
            acc[mf][nf], 0, 0, 0);
        acc[mf][nf] = __builtin_amdgcn_mfma_f32_16x16x32_bf16(
            __builtin_bit_cast(bf16x8, a_l[mf]), __builtin_bit_cast(bf16x8, b_h),
            acc[mf][nf], 0, 0, 0);
      }
    }
    if (kt < 15) cur = nxt;  // register move, uniform guard
  }
  // epilogue: C/D map col=lane&15, row=(lane>>4)*4+reg
#pragma unroll
  for (int mf = 0; mf < 4; ++mf) {
#pragma unroll
    for (int nf = 0; nf < 4; ++nf) {
      const int co = nf * 16 + (lane & 15);
#pragma unroll
      for (int rg = 0; rg < 4; ++rg) {
        const int mvox = mf * 16 + (lane >> 4) * 4 + rg;
        const int mz = mvox >> 4, my = (mvox >> 2) & 3, mx = mvox & 3;
        const int ovox = ((2 * mz + pz) * 8 + (2 * my + py)) * 8 + (2 * mx + px);
        float a = acc[mf][nf][rg];
        a = a > 0.f ? a : SLOPE * a;
        out[(((size_t)p * 16 + b) * 512 + ovox) * 64 + co] = a;
      }
    }
  }
}

// ---------------- L4: deconv 64->4, 8^3 -> 16^3, cls-PAIR merged (pz in {0,1}) ----------------
// in: h3 [p][b][512][64]; out: [b][p][4][16][16][16]
// 1-D grid 1024 = XCD-swizzled (p, clspair, bg); block 256
__global__ __launch_bounds__(256) void k_l4(const float* __restrict__ in,
    const float* __restrict__ w4, const float* __restrict__ b4,
    float* __restrict__ out) {
  __shared__ float inl[4][512][6];  // [b][8^3 input][ci-chunk 4 + pad2]
  __shared__ float wl[4][64][4];    // [ci-chunk][tap][co]
  const int t = threadIdx.x;
  const int wg = xcd_swz(blockIdx.x, 128);  // 1024 blocks: 128 per XCD chunk
  const int p = wg >> 4, cls0 = (wg >> 2) & 3, bg = wg & 3;  // 8 p's per XCD
  const int py = (cls0 >> 1) & 1, px = cls0 & 1;  // pz = cp (loop)

  float acc[2][4][2][4];
  float bv[4];
#pragma unroll
  for (int j = 0; j < 4; ++j) bv[j] = b4[p * 4 + j];
#pragma unroll
  for (int cp = 0; cp < 2; ++cp)
#pragma unroll
    for (int bi = 0; bi < 4; ++bi)
#pragma unroll
      for (int vi = 0; vi < 2; ++vi)
#pragma unroll
        for (int j = 0; j < 4; ++j) acc[cp][bi][vi][j] = bv[j];

  for (int ci0 = 0; ci0 < 64; ci0 += 4) {
    __syncthreads();
#pragma unroll
    for (int g4 = 0; g4 < 8; ++g4) {  // stage input: 2048 float4
      const int g = t + g4 * 256;
      const int iv = g & 511, bi = g >> 9;
      const float4 v =
          *(const float4*)(in + (((size_t)p * 16 + bg * 4 + bi) * 512 + iv) * 64 + ci0);
      float* d = &inl[bi][iv][0];
      d[0] = v.x; d[1] = v.y; d[2] = v.z; d[3] = v.w;
    }
    {  // stage weights: 256 float4
      const int t4 = t & 15, cc2 = (t >> 4) & 3, cc = t >> 6;
      const float4 v =
          *(const float4*)(w4 + (((size_t)p * 64 + ci0 + cc) * 4 + cc2) * 64 + t4 * 4);
      wl[cc][t4 * 4 + 0][cc2] = v.x; wl[cc][t4 * 4 + 1][cc2] = v.y;
      wl[cc][t4 * 4 + 2][cc2] = v.z; wl[cc][t4 * 4 + 3][cc2] = v.w;
    }
    __syncthreads();
#pragma unroll
    for (int s = 0; s < 8; ++s) {
      const int sz = (s >> 2) & 1, sy = (s >> 1) & 1, sx = s & 1;
      const int tyx = (3 - py - 2 * sy) * 4 + (3 - px - 2 * sx);
      const int tap0 = (3 - 2 * sz) * 16 + tyx;  // pz = 0
      const int tap1 = (2 - 2 * sz) * 16 + tyx;  // pz = 1
      float wsc[2][4][4];
#pragma unroll
      for (int cc = 0; cc < 4; ++cc)
#pragma unroll
        for (int j = 0; j < 4; ++j) {
          wsc[0][cc][j] = wl[cc][tap0][j];
          wsc[1][cc][j] = wl[cc][tap1][j];
        }
#pragma unroll
      for (int vi = 0; vi < 2; ++vi) {
        const int v = t + vi * 256;
        const int vz = v >> 6, vy = (v >> 3) & 7, vx = v & 7;
        const int iyv = vy + py + sy - 1, ixv = vx + px + sx - 1;
        const bool okyx = (unsigned)iyv < 8u && (unsigned)ixv < 8u;
#pragma unroll
        for (int cp = 0; cp < 2; ++cp) {
          const int izv = vz + cp + sz - 1;
          const bool ok = okyx && (unsigned)izv < 8u;
          const int ivf = ok ? (izv * 8 + iyv) * 8 + ixv : 0;
#pragma unroll
          for (int bi = 0; bi < 4; ++bi) {
            float2 a01 = *(const float2*)&inl[bi][ivf][0];
            float2 a23 = *(const float2*)&inl[bi][ivf][2];
            if (!ok) { a01.x = 0.f; a01.y = 0.f; a23.x = 0.f; a23.y = 0.f; }
#pragma unroll
            for (int j = 0; j < 4; ++j) {
              float a = acc[cp][bi][vi][j];
              a = fmaf(a01.x, wsc[cp][0][j], a);
              a = fmaf(a01.y, wsc[cp][1][j], a);
              a = fmaf(a23.x, wsc[cp][2][j], a);
              a = fmaf(a23.y, wsc[cp][3][j], a);
              acc[cp][bi][vi][j] = a;
            }
          }
        }
      }
    }
  }
  // epilogue: out[b][p][co][z][y][x]
#pragma unroll
  for (int vi = 0; vi < 2; ++vi) {
    const int v = t + vi * 256;
    const int vz = v >> 6, vy = (v >> 3) & 7, vx = v & 7;
    const int oy = 2 * vy + py, ox = 2 * vx + px;
#pragma unroll
    for (int cp = 0; cp < 2; ++cp) {
      const int oz = 2 * vz + cp;
      const int ovf = (oz * 16 + oy) * 16 + ox;
#pragma unroll
      for (int bi = 0; bi < 4; ++bi) {
        const int b = bg * 4 + bi;
#pragma unroll
        for (int j = 0; j < 4; ++j)
          out[(((size_t)b * 64 + p) * 4 + j) * 4096 + ovf] = acc[cp][bi][vi][j];
      }
    }
  }
}

extern "C" void kernel_launch(void* const* d_in, const int* in_sizes, int n_in,
                              void* d_out, int out_size, void* d_ws, size_t ws_size,
                              hipStream_t stream) {
  const float* x  = (const float*)d_in[0];
  const float* w0 = (const float*)d_in[1];
  const float* b0 = (const float*)d_in[2];
  const float* w1 = (const float*)d_in[3];
  const float* b1 = (const float*)d_in[4];
  const float* w2 = (const float*)d_in[5];
  const float* b2 = (const float*)d_in[6];
  const float* w3 = (const float*)d_in[7];
  const float* b3 = (const float*)d_in[8];
  const float* w4 = (const float*)d_in[9];
  const float* b4 = (const float*)d_in[10];

  float* ws = (float*)d_ws;
  float* h0 = ws;                               // 2048 f32
  float* h1 = h0 + 2048;                        // 1,048,576 f32
  float* h3 = h1 + 1048576;                     // 33,554,432 f32
  u16* h2hi  = (u16*)(h3 + 33554432);           // 4,194,304 u16
  u16* h2lo  = h2hi + 4194304;                  // 4,194,304 u16
  u16* wt3hi = h2lo + 4194304;                  // 16,777,216 u16
  u16* wt3lo = wt3hi + 16777216;                // 16,777,216 u16  (total ~222 MB)
  float* outp = (float*)d_out;

  k_dec0<<<dim3(16, 32), dim3(256), 0, stream>>>(x, w0, b0, h0);
  k_l1<<<dim3(4, 1, 64), dim3(256), 0, stream>>>(h0, w1, b1, h1);
  k_prep_w3<<<dim3(64, 4), dim3(256), 0, stream>>>(w3, wt3hi, wt3lo);
  k_deconv_split<128, 2><<<dim3(256), dim3(256), 0, stream>>>(h1, w2, b2, h2hi, h2lo);
  k_l3_mfma<<<dim3(2048), dim3(256), 0, stream>>>(h2hi, h2lo, wt3hi, wt3lo, b3, h3);
  k_l4<<<dim3(1024), dim3(256), 0, stream>>>(h3, w4, b4, outp);
}